// Round 1
// baseline (625.431 us; speedup 1.0000x reference)
//
#include <hip/hip_runtime.h>
#include <cstddef>

// ---------------------------------------------------------------------------
// MultiGroupDMoN forward, reduced algebraically:
//   trace(A S S^T-ish terms) = sum_e val * dot(S[src], S[dst])
//   deg @ S                  = sum_e val * S[dst, :]
//   m                        = sum_e val
// Kernels:
//   k_rows  : S = softmax(F@W+b) (write to d_out), cluster_sizes, P = S^T F
//   k_edges : per-graph {m, trace, gdS[16]} accumulators
//   k_final : losses + selu(P / cs) -> features_pooled, total_loss
// ws layout (floats): [0..4095] P, [4096..4111] cs, [4112..4165] 3 x {m,tr,gdS[16]}
// ---------------------------------------------------------------------------

__global__ void __launch_bounds__(256)
k_rows(const float* __restrict__ F, const float* __restrict__ W,
       const float* __restrict__ b, float* __restrict__ S_out,
       float* __restrict__ ws_P, float* __restrict__ ws_cs,
       int n, int n_tiles)
{
    __shared__ float Wt[16][260];     // W transposed, padded (bank spread)
    __shared__ float rows[16][260];   // 16 feature rows, padded
    __shared__ float S_lds[16][17];
    __shared__ float cs_red[256];

    const int t = threadIdx.x;

    for (int idx = t; idx < 4096; idx += 256)
        Wt[idx & 15][idx >> 4] = W[idx];          // Wt[k][d] = W[d][k]

    const float bk = b[t & 15];
    const int rl = t >> 4;       // logits phase: row within tile
    const int kl = t & 15;       // logits phase: cluster
    const int kp = t & 15;       // P phase: cluster
    const int cp = t >> 4;       // P phase: 16-wide d-chunk

    float4 P0 = {0,0,0,0}, P1 = {0,0,0,0}, P2 = {0,0,0,0}, P3 = {0,0,0,0};
    float cs_acc = 0.f;
    __syncthreads();

    for (int tile = blockIdx.x; tile < n_tiles; tile += gridDim.x) {
        const int row0 = tile << 4;
        const float4* F4 = (const float4*)(F + (size_t)row0 * 256);
        #pragma unroll
        for (int q = 0; q < 4; ++q) {
            int idx = t + (q << 8);              // 0..1023 float4 slots
            int r = idx >> 6, dc = idx & 63;
            float4 v = {0.f, 0.f, 0.f, 0.f};
            if (row0 + r < n) v = F4[idx];
            *(float4*)&rows[r][dc << 2] = v;
        }
        __syncthreads();

        // ---- logits: thread (rl, kl) computes F[row0+rl] . W[:,kl] ----
        float acc = 0.f;
        #pragma unroll 8
        for (int dd = 0; dd < 64; ++dd) {
            float4 f4 = *(const float4*)&rows[rl][dd << 2];
            float4 w4 = *(const float4*)&Wt[kl][dd << 2];
            acc = fmaf(f4.x, w4.x, acc);
            acc = fmaf(f4.y, w4.y, acc);
            acc = fmaf(f4.z, w4.z, acc);
            acc = fmaf(f4.w, w4.w, acc);
        }
        acc += bk;

        // ---- softmax over the 16 lanes of this row ----
        float mx = acc;
        #pragma unroll
        for (int o = 8; o; o >>= 1) mx = fmaxf(mx, __shfl_xor(mx, o, 16));
        float ev = __expf(acc - mx);
        float sm = ev;
        #pragma unroll
        for (int o = 8; o; o >>= 1) sm += __shfl_xor(sm, o, 16);
        float sval = ev / sm;

        const bool valid = (row0 + rl) < n;
        if (valid) {
            S_out[(((size_t)(row0 + rl)) << 4) + kl] = sval;  // coalesced
            cs_acc += sval;
        }
        S_lds[rl][kl] = valid ? sval : 0.f;
        __syncthreads();

        // ---- P accumulation: thread (kp,cp) owns P[kp][16cp..16cp+15] ----
        #pragma unroll 4
        for (int r = 0; r < 16; ++r) {
            float sv = S_lds[r][kp];
            const float* rp = &rows[r][cp << 4];
            float4 f0 = *(const float4*)&rp[0];
            float4 f1 = *(const float4*)&rp[4];
            float4 f2 = *(const float4*)&rp[8];
            float4 f3 = *(const float4*)&rp[12];
            P0.x = fmaf(sv, f0.x, P0.x); P0.y = fmaf(sv, f0.y, P0.y);
            P0.z = fmaf(sv, f0.z, P0.z); P0.w = fmaf(sv, f0.w, P0.w);
            P1.x = fmaf(sv, f1.x, P1.x); P1.y = fmaf(sv, f1.y, P1.y);
            P1.z = fmaf(sv, f1.z, P1.z); P1.w = fmaf(sv, f1.w, P1.w);
            P2.x = fmaf(sv, f2.x, P2.x); P2.y = fmaf(sv, f2.y, P2.y);
            P2.z = fmaf(sv, f2.z, P2.z); P2.w = fmaf(sv, f2.w, P2.w);
            P3.x = fmaf(sv, f3.x, P3.x); P3.y = fmaf(sv, f3.y, P3.y);
            P3.z = fmaf(sv, f3.z, P3.z); P3.w = fmaf(sv, f3.w, P3.w);
        }
        __syncthreads();   // before next tile overwrites rows[]
    }

    // ---- flush P partials ----
    {
        float* dst = ws_P + kp * 256 + (cp << 4);
        atomicAdd(dst + 0,  P0.x); atomicAdd(dst + 1,  P0.y);
        atomicAdd(dst + 2,  P0.z); atomicAdd(dst + 3,  P0.w);
        atomicAdd(dst + 4,  P1.x); atomicAdd(dst + 5,  P1.y);
        atomicAdd(dst + 6,  P1.z); atomicAdd(dst + 7,  P1.w);
        atomicAdd(dst + 8,  P2.x); atomicAdd(dst + 9,  P2.y);
        atomicAdd(dst + 10, P2.z); atomicAdd(dst + 11, P2.w);
        atomicAdd(dst + 12, P3.x); atomicAdd(dst + 13, P3.y);
        atomicAdd(dst + 14, P3.z); atomicAdd(dst + 15, P3.w);
    }
    // ---- cluster sizes ----
    cs_red[t] = cs_acc;
    __syncthreads();
    if (t < 16) {
        float ssum = 0.f;
        #pragma unroll
        for (int i = 0; i < 16; ++i) ssum += cs_red[t + (i << 4)];
        atomicAdd(&ws_cs[t], ssum);
    }
}

__global__ void __launch_bounds__(256)
k_edges(const int* __restrict__ src, const int* __restrict__ dst,
        const float* __restrict__ val, const float* __restrict__ S,
        float* __restrict__ out18, int nE)
{
    float m_acc = 0.f, tr_acc = 0.f;
    float gds[16];
    #pragma unroll
    for (int k = 0; k < 16; ++k) gds[k] = 0.f;

    const int stride = gridDim.x * 256;
    for (int e = blockIdx.x * 256 + threadIdx.x; e < nE; e += stride) {
        int si = src[e], di = dst[e];
        float v = val[e];
        const float4* Ss = (const float4*)(S + ((size_t)si << 4));
        const float4* Sd = (const float4*)(S + ((size_t)di << 4));
        float4 a0 = Ss[0], a1 = Ss[1], a2 = Ss[2], a3 = Ss[3];
        float4 b0 = Sd[0], b1 = Sd[1], b2 = Sd[2], b3 = Sd[3];
        float dot = a0.x*b0.x + a0.y*b0.y + a0.z*b0.z + a0.w*b0.w
                  + a1.x*b1.x + a1.y*b1.y + a1.z*b1.z + a1.w*b1.w
                  + a2.x*b2.x + a2.y*b2.y + a2.z*b2.z + a2.w*b2.w
                  + a3.x*b3.x + a3.y*b3.y + a3.z*b3.z + a3.w*b3.w;
        m_acc += v;
        tr_acc = fmaf(v, dot, tr_acc);
        gds[0]  = fmaf(v, b0.x, gds[0]);  gds[1]  = fmaf(v, b0.y, gds[1]);
        gds[2]  = fmaf(v, b0.z, gds[2]);  gds[3]  = fmaf(v, b0.w, gds[3]);
        gds[4]  = fmaf(v, b1.x, gds[4]);  gds[5]  = fmaf(v, b1.y, gds[5]);
        gds[6]  = fmaf(v, b1.z, gds[6]);  gds[7]  = fmaf(v, b1.w, gds[7]);
        gds[8]  = fmaf(v, b2.x, gds[8]);  gds[9]  = fmaf(v, b2.y, gds[9]);
        gds[10] = fmaf(v, b2.z, gds[10]); gds[11] = fmaf(v, b2.w, gds[11]);
        gds[12] = fmaf(v, b3.x, gds[12]); gds[13] = fmaf(v, b3.y, gds[13]);
        gds[14] = fmaf(v, b3.z, gds[14]); gds[15] = fmaf(v, b3.w, gds[15]);
    }

    // wave reduction (64 lanes)
    #pragma unroll
    for (int o = 32; o; o >>= 1) {
        m_acc  += __shfl_xor(m_acc, o);
        tr_acc += __shfl_xor(tr_acc, o);
        #pragma unroll
        for (int k = 0; k < 16; ++k) gds[k] += __shfl_xor(gds[k], o);
    }
    __shared__ float wred[4][18];
    const int wid = threadIdx.x >> 6, lane = threadIdx.x & 63;
    if (lane == 0) {
        wred[wid][0] = m_acc; wred[wid][1] = tr_acc;
        #pragma unroll
        for (int k = 0; k < 16; ++k) wred[wid][2 + k] = gds[k];
    }
    __syncthreads();
    if (threadIdx.x < 18) {
        float s = wred[0][threadIdx.x] + wred[1][threadIdx.x]
                + wred[2][threadIdx.x] + wred[3][threadIdx.x];
        atomicAdd(&out18[threadIdx.x], s);
    }
}

__global__ void __launch_bounds__(256)
k_final(const float* __restrict__ ws, const void* __restrict__ lamda_ptr,
        float* __restrict__ out, int n)
{
    const float* P  = ws;
    const float* cs = ws + 4096;
    const float* G  = ws + 4112;   // 3 x 18
    const int t = threadIdx.x;

    const float scale = 1.0507009873554805f;
    const float alpha = 1.6732632423543772f;
    for (int idx = t; idx < 4096; idx += 256) {
        int k = idx >> 8;
        float x = P[idx] / cs[k];
        float y = x > 0.f ? scale * x : scale * alpha * (expf(x) - 1.f);
        out[idx] = y;
    }

    if (t == 0) {
        int   li = *(const int*)lamda_ptr;
        float lf = *(const float*)lamda_ptr;
        float lamda = (li > -100000 && li < 100000) ? (float)li : lf;

        float m = G[0], trA = G[1];
        float ds2 = 0.f;
        for (int k = 0; k < 16; ++k) ds2 += G[2 + k] * G[2 + k];
        float spectral = -(trA - ds2 / (2.f * m)) / (2.f * m);

        float Q[2], gm[2];
        for (int g = 0; g < 2; ++g) {
            const float* Gg = G + 18 * (g + 1);
            float mg = Gg[0], trg = Gg[1];
            float gds2 = 0.f;
            for (int k = 0; k < 16; ++k) gds2 += Gg[2 + k] * Gg[2 + k];
            float safe = mg > 0.f ? mg : 1.f;
            float q = (trg - gds2 / (2.f * safe)) / (2.f * m);
            Q[g]  = mg > 0.f ? q : 0.f;
            gm[g] = mg;
        }
        float Qmin = fminf(Q[0], Q[1]);
        float gmean = 0.5f * (gm[0] + gm[1]);
        float fairness = (m / (gmean + 1e-8f)) * (-Qmin);

        float csn = 0.f;
        for (int k = 0; k < 16; ++k) csn += cs[k] * cs[k];
        float collapse = (sqrtf(csn) / (float)n) * 4.f - 1.f;   // sqrt(16)=4

        out[4096 + (size_t)n * 16] = spectral + lamda * fairness + 0.1f * collapse;
    }
}

extern "C" void kernel_launch(void* const* d_in, const int* in_sizes, int n_in,
                              void* d_out, int out_size, void* d_ws, size_t ws_size,
                              hipStream_t stream)
{
    const float* F       = (const float*)d_in[0];
    const float* W       = (const float*)d_in[1];
    const float* b       = (const float*)d_in[2];
    const int*   adj_src = (const int*)d_in[3];
    const int*   adj_dst = (const int*)d_in[4];
    const float* adj_val = (const float*)d_in[5];
    const int*   g1_src  = (const int*)d_in[6];
    const int*   g1_dst  = (const int*)d_in[7];
    const float* g1_val  = (const float*)d_in[8];
    const int*   g2_src  = (const int*)d_in[9];
    const int*   g2_dst  = (const int*)d_in[10];
    const float* g2_val  = (const float*)d_in[11];
    const void*  lamda_p = d_in[12];

    const int n  = in_sizes[0] / 256;
    const int nE = in_sizes[3];
    const int n1 = in_sizes[6];
    const int n2 = in_sizes[9];

    float* out   = (float*)d_out;
    float* S_out = out + 4096;          // S lives directly in d_out
    float* ws    = (float*)d_ws;

    hipMemsetAsync(d_ws, 0, (4096 + 16 + 54) * sizeof(float), stream);

    const int n_tiles = (n + 15) >> 4;
    int grid1 = n_tiles < 1024 ? n_tiles : 1024;
    k_rows<<<grid1, 256, 0, stream>>>(F, W, b, S_out, ws, ws + 4096, n, n_tiles);

    auto eg = [](int ne) { int g = (ne + 255) / 256; return g < 2048 ? g : 2048; };
    k_edges<<<eg(nE), 256, 0, stream>>>(adj_src, adj_dst, adj_val, S_out, ws + 4112, nE);
    k_edges<<<eg(n1), 256, 0, stream>>>(g1_src, g1_dst, g1_val, S_out, ws + 4130, n1);
    k_edges<<<eg(n2), 256, 0, stream>>>(g2_src, g2_dst, g2_val, S_out, ws + 4148, n2);

    k_final<<<1, 256, 0, stream>>>(ws, lamda_p, out, n);
}

// Round 2
// 349.434 us; speedup vs baseline: 1.7898x; 1.7898x over previous
//
#include <hip/hip_runtime.h>
#include <cstddef>

// ---------------------------------------------------------------------------
// MultiGroupDMoN forward, reduced algebraically:
//   trace(S^T A S)  = sum_e val * dot(S[src], S[dst])
//   deg @ S         = sum_e val * S[dst, :]
//   m               = sum_e val
// R2: no contended atomics. Per-block partials in ws + reduce kernels.
// ws layout (floats):
//   [0 .. G1*4112)                 per-block k_rows partials (4096 P + 16 cs)
//   [OFF_E .. OFF_E+3*18*2048)     k_edges partials, [g][slot][block]
//   [OFF_R .. OFF_R+4112)          reduced P[4096] + cs[16]
// ---------------------------------------------------------------------------

#define G1_MAX   1024
#define EGRID    2048
#define OFF_E    ((size_t)G1_MAX * 4112)
#define OFF_R    (OFF_E + (size_t)3 * 18 * EGRID)

__global__ void __launch_bounds__(256)
k_rows(const float* __restrict__ F, const float* __restrict__ W,
       const float* __restrict__ b, float* __restrict__ S_out,
       float* __restrict__ ws_P, int n, int n_tiles)
{
    __shared__ float Wt[16][260];     // W transposed, padded
    __shared__ float rows[16][260];   // 16 feature rows, padded
    __shared__ float S_lds[16][17];
    __shared__ float cs_red[256];

    const int t = threadIdx.x;

    for (int idx = t; idx < 4096; idx += 256)
        Wt[idx & 15][idx >> 4] = W[idx];          // Wt[k][d] = W[d][k]

    const float bk = b[t & 15];
    const int rl = t >> 4;       // logits phase: row within tile
    const int kl = t & 15;       // logits phase: cluster
    const int kp = t & 15;       // P phase: cluster
    const int cp = t >> 4;       // P phase: 16-wide d-chunk

    float4 P0 = {0,0,0,0}, P1 = {0,0,0,0}, P2 = {0,0,0,0}, P3 = {0,0,0,0};
    float cs_acc = 0.f;
    __syncthreads();

    for (int tile = blockIdx.x; tile < n_tiles; tile += gridDim.x) {
        const int row0 = tile << 4;
        const float4* F4 = (const float4*)(F + (size_t)row0 * 256);
        #pragma unroll
        for (int q = 0; q < 4; ++q) {
            int idx = t + (q << 8);              // 0..1023 float4 slots
            int r = idx >> 6, dc = idx & 63;
            float4 v = {0.f, 0.f, 0.f, 0.f};
            if (row0 + r < n) v = F4[idx];
            *(float4*)&rows[r][dc << 2] = v;
        }
        __syncthreads();

        // ---- logits: thread (rl, kl) computes F[row0+rl] . W[:,kl] ----
        float acc = 0.f;
        #pragma unroll 8
        for (int dd = 0; dd < 64; ++dd) {
            float4 f4 = *(const float4*)&rows[rl][dd << 2];
            float4 w4 = *(const float4*)&Wt[kl][dd << 2];
            acc = fmaf(f4.x, w4.x, acc);
            acc = fmaf(f4.y, w4.y, acc);
            acc = fmaf(f4.z, w4.z, acc);
            acc = fmaf(f4.w, w4.w, acc);
        }
        acc += bk;

        // ---- softmax over the 16 lanes of this row ----
        float mx = acc;
        #pragma unroll
        for (int o = 8; o; o >>= 1) mx = fmaxf(mx, __shfl_xor(mx, o, 16));
        float ev = __expf(acc - mx);
        float sm = ev;
        #pragma unroll
        for (int o = 8; o; o >>= 1) sm += __shfl_xor(sm, o, 16);
        float sval = ev / sm;

        const bool valid = (row0 + rl) < n;
        if (valid) {
            S_out[(((size_t)(row0 + rl)) << 4) + kl] = sval;  // coalesced
            cs_acc += sval;
        }
        S_lds[rl][kl] = valid ? sval : 0.f;
        __syncthreads();

        // ---- P accumulation: thread (kp,cp) owns P[kp][16cp..16cp+15] ----
        #pragma unroll 4
        for (int r = 0; r < 16; ++r) {
            float sv = S_lds[r][kp];
            const float* rp = &rows[r][cp << 4];
            float4 f0 = *(const float4*)&rp[0];
            float4 f1 = *(const float4*)&rp[4];
            float4 f2 = *(const float4*)&rp[8];
            float4 f3 = *(const float4*)&rp[12];
            P0.x = fmaf(sv, f0.x, P0.x); P0.y = fmaf(sv, f0.y, P0.y);
            P0.z = fmaf(sv, f0.z, P0.z); P0.w = fmaf(sv, f0.w, P0.w);
            P1.x = fmaf(sv, f1.x, P1.x); P1.y = fmaf(sv, f1.y, P1.y);
            P1.z = fmaf(sv, f1.z, P1.z); P1.w = fmaf(sv, f1.w, P1.w);
            P2.x = fmaf(sv, f2.x, P2.x); P2.y = fmaf(sv, f2.y, P2.y);
            P2.z = fmaf(sv, f2.z, P2.z); P2.w = fmaf(sv, f2.w, P2.w);
            P3.x = fmaf(sv, f3.x, P3.x); P3.y = fmaf(sv, f3.y, P3.y);
            P3.z = fmaf(sv, f3.z, P3.z); P3.w = fmaf(sv, f3.w, P3.w);
        }
        __syncthreads();   // before next tile overwrites rows[]
    }

    // ---- flush partials to private per-block slot (NO atomics) ----
    {
        float* dst = ws_P + (size_t)blockIdx.x * 4112 + kp * 256 + (cp << 4);
        *(float4*)&dst[0]  = P0;
        *(float4*)&dst[4]  = P1;
        *(float4*)&dst[8]  = P2;
        *(float4*)&dst[12] = P3;
    }
    cs_red[t] = cs_acc;
    __syncthreads();
    if (t < 16) {
        float ssum = 0.f;
        #pragma unroll
        for (int i = 0; i < 16; ++i) ssum += cs_red[t + (i << 4)];
        ws_P[(size_t)blockIdx.x * 4112 + 4096 + t] = ssum;
    }
}

// sums nb per-block partials (stride 4112) into ws_red[0..4111]
// grid = 17 * NSEG blocks; low-contention atomics (NSEG per address)
#define NSEG 16
__global__ void __launch_bounds__(256)
k_reduce(const float* __restrict__ ws_P, float* __restrict__ ws_red, int nb)
{
    const int seg  = blockIdx.x & (NSEG - 1);
    const int jblk = blockIdx.x / NSEG;
    const int idx  = jblk * 256 + threadIdx.x;
    if (idx >= 4112) return;
    const int chunk = (nb + NSEG - 1) / NSEG;
    const int b0 = seg * chunk;
    const int b1 = min(nb, b0 + chunk);
    float s = 0.f;
    for (int bb = b0; bb < b1; ++bb)
        s += ws_P[(size_t)bb * 4112 + idx];
    atomicAdd(&ws_red[idx], s);
}

__global__ void __launch_bounds__(256)
k_edges(const int* __restrict__ src, const int* __restrict__ dst,
        const float* __restrict__ val, const float* __restrict__ S,
        float* __restrict__ ws_e, int nE)
{
    float m_acc = 0.f, tr_acc = 0.f;
    float gds[16];
    #pragma unroll
    for (int k = 0; k < 16; ++k) gds[k] = 0.f;

    const int stride = gridDim.x * 256;
    for (int e = blockIdx.x * 256 + threadIdx.x; e < nE; e += stride) {
        int si = src[e], di = dst[e];
        float v = val[e];
        const float4* Ss = (const float4*)(S + ((size_t)si << 4));
        const float4* Sd = (const float4*)(S + ((size_t)di << 4));
        float4 a0 = Ss[0], a1 = Ss[1], a2 = Ss[2], a3 = Ss[3];
        float4 b0 = Sd[0], b1 = Sd[1], b2 = Sd[2], b3 = Sd[3];
        float dot = a0.x*b0.x + a0.y*b0.y + a0.z*b0.z + a0.w*b0.w
                  + a1.x*b1.x + a1.y*b1.y + a1.z*b1.z + a1.w*b1.w
                  + a2.x*b2.x + a2.y*b2.y + a2.z*b2.z + a2.w*b2.w
                  + a3.x*b3.x + a3.y*b3.y + a3.z*b3.z + a3.w*b3.w;
        m_acc += v;
        tr_acc = fmaf(v, dot, tr_acc);
        gds[0]  = fmaf(v, b0.x, gds[0]);  gds[1]  = fmaf(v, b0.y, gds[1]);
        gds[2]  = fmaf(v, b0.z, gds[2]);  gds[3]  = fmaf(v, b0.w, gds[3]);
        gds[4]  = fmaf(v, b1.x, gds[4]);  gds[5]  = fmaf(v, b1.y, gds[5]);
        gds[6]  = fmaf(v, b1.z, gds[6]);  gds[7]  = fmaf(v, b1.w, gds[7]);
        gds[8]  = fmaf(v, b2.x, gds[8]);  gds[9]  = fmaf(v, b2.y, gds[9]);
        gds[10] = fmaf(v, b2.z, gds[10]); gds[11] = fmaf(v, b2.w, gds[11]);
        gds[12] = fmaf(v, b3.x, gds[12]); gds[13] = fmaf(v, b3.y, gds[13]);
        gds[14] = fmaf(v, b3.z, gds[14]); gds[15] = fmaf(v, b3.w, gds[15]);
    }

    // wave reduction (64 lanes)
    #pragma unroll
    for (int o = 32; o; o >>= 1) {
        m_acc  += __shfl_xor(m_acc, o);
        tr_acc += __shfl_xor(tr_acc, o);
        #pragma unroll
        for (int k = 0; k < 16; ++k) gds[k] += __shfl_xor(gds[k], o);
    }
    __shared__ float wred[4][18];
    const int wid = threadIdx.x >> 6, lane = threadIdx.x & 63;
    if (lane == 0) {
        wred[wid][0] = m_acc; wred[wid][1] = tr_acc;
        #pragma unroll
        for (int k = 0; k < 16; ++k) wred[wid][2 + k] = gds[k];
    }
    __syncthreads();
    if (threadIdx.x < 18) {
        float s = wred[0][threadIdx.x] + wred[1][threadIdx.x]
                + wred[2][threadIdx.x] + wred[3][threadIdx.x];
        // transposed layout [slot][block] so k_final reduce is coalesced
        ws_e[(size_t)threadIdx.x * EGRID + blockIdx.x] = s;
    }
}

__global__ void __launch_bounds__(256)
k_final(const float* __restrict__ ws_red, const float* __restrict__ ws_e,
        const void* __restrict__ lamda_ptr, float* __restrict__ out,
        int n, int g0, int g1, int g2)
{
    __shared__ float G[54];
    const int t = threadIdx.x, lane = t & 63, w = t >> 6;

    // wave-reduce edge partials: pair p = (g, slot)
    int grids[3] = {g0, g1, g2};
    for (int p = w; p < 54; p += 4) {
        int g = p / 18, slot = p % 18;
        const float* base = ws_e + (size_t)g * 18 * EGRID + (size_t)slot * EGRID;
        int gb = grids[g];
        float s = 0.f;
        for (int bb = lane; bb < gb; bb += 64) s += base[bb];
        #pragma unroll
        for (int o = 32; o; o >>= 1) s += __shfl_xor(s, o);
        if (lane == 0) G[p] = s;
    }
    __syncthreads();

    const float* P  = ws_red;
    const float* cs = ws_red + 4096;

    const float scale = 1.0507009873554805f;
    const float alpha = 1.6732632423543772f;
    for (int idx = t; idx < 4096; idx += 256) {
        int k = idx >> 8;
        float x = P[idx] / cs[k];
        float y = x > 0.f ? scale * x : scale * alpha * (expf(x) - 1.f);
        out[idx] = y;
    }

    if (t == 0) {
        int   li = *(const int*)lamda_ptr;
        float lf = *(const float*)lamda_ptr;
        float lamda = (li > -100000 && li < 100000) ? (float)li : lf;

        float m = G[0], trA = G[1];
        float ds2 = 0.f;
        for (int k = 0; k < 16; ++k) ds2 += G[2 + k] * G[2 + k];
        float spectral = -(trA - ds2 / (2.f * m)) / (2.f * m);

        float Q[2], gm[2];
        for (int g = 0; g < 2; ++g) {
            const float* Gg = G + 18 * (g + 1);
            float mg = Gg[0], trg = Gg[1];
            float gds2 = 0.f;
            for (int k = 0; k < 16; ++k) gds2 += Gg[2 + k] * Gg[2 + k];
            float safe = mg > 0.f ? mg : 1.f;
            float q = (trg - gds2 / (2.f * safe)) / (2.f * m);
            Q[g]  = mg > 0.f ? q : 0.f;
            gm[g] = mg;
        }
        float Qmin = fminf(Q[0], Q[1]);
        float gmean = 0.5f * (gm[0] + gm[1]);
        float fairness = (m / (gmean + 1e-8f)) * (-Qmin);

        float csn = 0.f;
        for (int k = 0; k < 16; ++k) csn += cs[k] * cs[k];
        float collapse = (sqrtf(csn) / (float)n) * 4.f - 1.f;   // sqrt(16)=4

        out[4096 + (size_t)n * 16] = spectral + lamda * fairness + 0.1f * collapse;
    }
}

extern "C" void kernel_launch(void* const* d_in, const int* in_sizes, int n_in,
                              void* d_out, int out_size, void* d_ws, size_t ws_size,
                              hipStream_t stream)
{
    const float* F       = (const float*)d_in[0];
    const float* W       = (const float*)d_in[1];
    const float* b       = (const float*)d_in[2];
    const int*   adj_src = (const int*)d_in[3];
    const int*   adj_dst = (const int*)d_in[4];
    const float* adj_val = (const float*)d_in[5];
    const int*   g1_src  = (const int*)d_in[6];
    const int*   g1_dst  = (const int*)d_in[7];
    const float* g1_val  = (const float*)d_in[8];
    const int*   g2_src  = (const int*)d_in[9];
    const int*   g2_dst  = (const int*)d_in[10];
    const float* g2_val  = (const float*)d_in[11];
    const void*  lamda_p = d_in[12];

    const int n  = in_sizes[0] / 256;
    const int nE = in_sizes[3];
    const int n1 = in_sizes[6];
    const int n2 = in_sizes[9];

    float* out   = (float*)d_out;
    float* S_out = out + 4096;          // S lives directly in d_out
    float* ws    = (float*)d_ws;
    float* ws_e  = ws + OFF_E;
    float* ws_r  = ws + OFF_R;

    const int n_tiles = (n + 15) >> 4;
    // fit per-block partials into ws
    long avail = ((long)(ws_size / 4) - (long)OFF_E < 0) ? 1
               : ((long)(ws_size / 4) - (long)(OFF_E + (size_t)3 * 18 * EGRID + 4112)) / 4112;
    int grid1 = n_tiles < G1_MAX ? n_tiles : G1_MAX;
    if (avail >= 1 && grid1 > avail) grid1 = (int)avail;
    if (grid1 < 1) grid1 = 1;

    k_rows<<<grid1, 256, 0, stream>>>(F, W, b, S_out, ws, n, n_tiles);

    hipMemsetAsync(ws_r, 0, 4112 * sizeof(float), stream);
    k_reduce<<<17 * NSEG, 256, 0, stream>>>(ws, ws_r, grid1);

    auto eg = [](int ne) { int g = (ne + 255) / 256; return g < EGRID ? g : EGRID; };
    k_edges<<<eg(nE), 256, 0, stream>>>(adj_src, adj_dst, adj_val, S_out,
                                        ws_e + (size_t)0 * 18 * EGRID, nE);
    k_edges<<<eg(n1), 256, 0, stream>>>(g1_src, g1_dst, g1_val, S_out,
                                        ws_e + (size_t)1 * 18 * EGRID, n1);
    k_edges<<<eg(n2), 256, 0, stream>>>(g2_src, g2_dst, g2_val, S_out,
                                        ws_e + (size_t)2 * 18 * EGRID, n2);

    k_final<<<1, 256, 0, stream>>>(ws_r, ws_e, lamda_p, out, n, eg(nE), eg(n1), eg(n2));
}

// Round 3
// 216.582 us; speedup vs baseline: 2.8877x; 1.6134x over previous
//
#include <hip/hip_runtime.h>
#include <cstddef>

// ---------------------------------------------------------------------------
// MultiGroupDMoN forward, reduced algebraically:
//   trace(S^T A S)  = sum_e val * dot(S[src], S[dst])
//   deg @ S         = sum_e val * S[dst, :]
//   m               = sum_e val
// R3: add k_ereduce tree stage (54 blocks) so k_final isn't a 1-block
//     latency-bound reduction over 54x2048 partials.
// ws layout (floats):
//   [0 .. G1*4112)                 per-block k_rows partials (4096 P + 16 cs)
//   [OFF_E .. OFF_E+3*18*EGRID)    k_edges partials, [g][slot][block]
//   [OFF_R .. OFF_R+4112)          reduced P[4096] + cs[16]
//   [OFF_G .. OFF_G+54)            reduced edge accumulators 3 x {m,tr,gdS16}
// ---------------------------------------------------------------------------

#define G1_MAX   1024
#define EGRID    2048
#define OFF_E    ((size_t)G1_MAX * 4112)
#define OFF_R    (OFF_E + (size_t)3 * 18 * EGRID)
#define OFF_G    (OFF_R + 4112)

__global__ void __launch_bounds__(256)
k_rows(const float* __restrict__ F, const float* __restrict__ W,
       const float* __restrict__ b, float* __restrict__ S_out,
       float* __restrict__ ws_P, int n, int n_tiles)
{
    __shared__ float Wt[16][260];     // W transposed, padded
    __shared__ float rows[16][260];   // 16 feature rows, padded
    __shared__ float S_lds[16][17];
    __shared__ float cs_red[256];

    const int t = threadIdx.x;

    for (int idx = t; idx < 4096; idx += 256)
        Wt[idx & 15][idx >> 4] = W[idx];          // Wt[k][d] = W[d][k]

    const float bk = b[t & 15];
    const int rl = t >> 4;       // logits phase: row within tile
    const int kl = t & 15;       // logits phase: cluster
    const int kp = t & 15;       // P phase: cluster
    const int cp = t >> 4;       // P phase: 16-wide d-chunk

    float4 P0 = {0,0,0,0}, P1 = {0,0,0,0}, P2 = {0,0,0,0}, P3 = {0,0,0,0};
    float cs_acc = 0.f;
    __syncthreads();

    for (int tile = blockIdx.x; tile < n_tiles; tile += gridDim.x) {
        const int row0 = tile << 4;
        const float4* F4 = (const float4*)(F + (size_t)row0 * 256);
        #pragma unroll
        for (int q = 0; q < 4; ++q) {
            int idx = t + (q << 8);              // 0..1023 float4 slots
            int r = idx >> 6, dc = idx & 63;
            float4 v = {0.f, 0.f, 0.f, 0.f};
            if (row0 + r < n) v = F4[idx];
            *(float4*)&rows[r][dc << 2] = v;
        }
        __syncthreads();

        // ---- logits: thread (rl, kl) computes F[row0+rl] . W[:,kl] ----
        float acc = 0.f;
        #pragma unroll 8
        for (int dd = 0; dd < 64; ++dd) {
            float4 f4 = *(const float4*)&rows[rl][dd << 2];
            float4 w4 = *(const float4*)&Wt[kl][dd << 2];
            acc = fmaf(f4.x, w4.x, acc);
            acc = fmaf(f4.y, w4.y, acc);
            acc = fmaf(f4.z, w4.z, acc);
            acc = fmaf(f4.w, w4.w, acc);
        }
        acc += bk;

        // ---- softmax over the 16 lanes of this row ----
        float mx = acc;
        #pragma unroll
        for (int o = 8; o; o >>= 1) mx = fmaxf(mx, __shfl_xor(mx, o, 16));
        float ev = __expf(acc - mx);
        float sm = ev;
        #pragma unroll
        for (int o = 8; o; o >>= 1) sm += __shfl_xor(sm, o, 16);
        float sval = ev / sm;

        const bool valid = (row0 + rl) < n;
        if (valid) {
            S_out[(((size_t)(row0 + rl)) << 4) + kl] = sval;  // coalesced
            cs_acc += sval;
        }
        S_lds[rl][kl] = valid ? sval : 0.f;
        __syncthreads();

        // ---- P accumulation: thread (kp,cp) owns P[kp][16cp..16cp+15] ----
        #pragma unroll 4
        for (int r = 0; r < 16; ++r) {
            float sv = S_lds[r][kp];
            const float* rp = &rows[r][cp << 4];
            float4 f0 = *(const float4*)&rp[0];
            float4 f1 = *(const float4*)&rp[4];
            float4 f2 = *(const float4*)&rp[8];
            float4 f3 = *(const float4*)&rp[12];
            P0.x = fmaf(sv, f0.x, P0.x); P0.y = fmaf(sv, f0.y, P0.y);
            P0.z = fmaf(sv, f0.z, P0.z); P0.w = fmaf(sv, f0.w, P0.w);
            P1.x = fmaf(sv, f1.x, P1.x); P1.y = fmaf(sv, f1.y, P1.y);
            P1.z = fmaf(sv, f1.z, P1.z); P1.w = fmaf(sv, f1.w, P1.w);
            P2.x = fmaf(sv, f2.x, P2.x); P2.y = fmaf(sv, f2.y, P2.y);
            P2.z = fmaf(sv, f2.z, P2.z); P2.w = fmaf(sv, f2.w, P2.w);
            P3.x = fmaf(sv, f3.x, P3.x); P3.y = fmaf(sv, f3.y, P3.y);
            P3.z = fmaf(sv, f3.z, P3.z); P3.w = fmaf(sv, f3.w, P3.w);
        }
        __syncthreads();   // before next tile overwrites rows[]
    }

    // ---- flush partials to private per-block slot (NO atomics) ----
    {
        float* dst = ws_P + (size_t)blockIdx.x * 4112 + kp * 256 + (cp << 4);
        *(float4*)&dst[0]  = P0;
        *(float4*)&dst[4]  = P1;
        *(float4*)&dst[8]  = P2;
        *(float4*)&dst[12] = P3;
    }
    cs_red[t] = cs_acc;
    __syncthreads();
    if (t < 16) {
        float ssum = 0.f;
        #pragma unroll
        for (int i = 0; i < 16; ++i) ssum += cs_red[t + (i << 4)];
        ws_P[(size_t)blockIdx.x * 4112 + 4096 + t] = ssum;
    }
}

// sums nb per-block partials (stride 4112) into ws_red[0..4111]
#define NSEG 16
__global__ void __launch_bounds__(256)
k_reduce(const float* __restrict__ ws_P, float* __restrict__ ws_red, int nb)
{
    const int seg  = blockIdx.x & (NSEG - 1);
    const int jblk = blockIdx.x / NSEG;
    const int idx  = jblk * 256 + threadIdx.x;
    if (idx >= 4112) return;
    const int chunk = (nb + NSEG - 1) / NSEG;
    const int b0 = seg * chunk;
    const int b1 = min(nb, b0 + chunk);
    float s = 0.f;
    for (int bb = b0; bb < b1; ++bb)
        s += ws_P[(size_t)bb * 4112 + idx];
    atomicAdd(&ws_red[idx], s);
}

__global__ void __launch_bounds__(256)
k_edges(const int* __restrict__ src, const int* __restrict__ dst,
        const float* __restrict__ val, const float* __restrict__ S,
        float* __restrict__ ws_e, int nE)
{
    float m_acc = 0.f, tr_acc = 0.f;
    float gds[16];
    #pragma unroll
    for (int k = 0; k < 16; ++k) gds[k] = 0.f;

    const int stride = gridDim.x * 256;
    for (int e = blockIdx.x * 256 + threadIdx.x; e < nE; e += stride) {
        int si = src[e], di = dst[e];
        float v = val[e];
        const float4* Ss = (const float4*)(S + ((size_t)si << 4));
        const float4* Sd = (const float4*)(S + ((size_t)di << 4));
        float4 a0 = Ss[0], a1 = Ss[1], a2 = Ss[2], a3 = Ss[3];
        float4 b0 = Sd[0], b1 = Sd[1], b2 = Sd[2], b3 = Sd[3];
        float dot = a0.x*b0.x + a0.y*b0.y + a0.z*b0.z + a0.w*b0.w
                  + a1.x*b1.x + a1.y*b1.y + a1.z*b1.z + a1.w*b1.w
                  + a2.x*b2.x + a2.y*b2.y + a2.z*b2.z + a2.w*b2.w
                  + a3.x*b3.x + a3.y*b3.y + a3.z*b3.z + a3.w*b3.w;
        m_acc += v;
        tr_acc = fmaf(v, dot, tr_acc);
        gds[0]  = fmaf(v, b0.x, gds[0]);  gds[1]  = fmaf(v, b0.y, gds[1]);
        gds[2]  = fmaf(v, b0.z, gds[2]);  gds[3]  = fmaf(v, b0.w, gds[3]);
        gds[4]  = fmaf(v, b1.x, gds[4]);  gds[5]  = fmaf(v, b1.y, gds[5]);
        gds[6]  = fmaf(v, b1.z, gds[6]);  gds[7]  = fmaf(v, b1.w, gds[7]);
        gds[8]  = fmaf(v, b2.x, gds[8]);  gds[9]  = fmaf(v, b2.y, gds[9]);
        gds[10] = fmaf(v, b2.z, gds[10]); gds[11] = fmaf(v, b2.w, gds[11]);
        gds[12] = fmaf(v, b3.x, gds[12]); gds[13] = fmaf(v, b3.y, gds[13]);
        gds[14] = fmaf(v, b3.z, gds[14]); gds[15] = fmaf(v, b3.w, gds[15]);
    }

    // wave reduction (64 lanes)
    #pragma unroll
    for (int o = 32; o; o >>= 1) {
        m_acc  += __shfl_xor(m_acc, o);
        tr_acc += __shfl_xor(tr_acc, o);
        #pragma unroll
        for (int k = 0; k < 16; ++k) gds[k] += __shfl_xor(gds[k], o);
    }
    __shared__ float wred[4][18];
    const int wid = threadIdx.x >> 6, lane = threadIdx.x & 63;
    if (lane == 0) {
        wred[wid][0] = m_acc; wred[wid][1] = tr_acc;
        #pragma unroll
        for (int k = 0; k < 16; ++k) wred[wid][2 + k] = gds[k];
    }
    __syncthreads();
    if (threadIdx.x < 18) {
        float s = wred[0][threadIdx.x] + wred[1][threadIdx.x]
                + wred[2][threadIdx.x] + wred[3][threadIdx.x];
        // transposed layout [slot][block] so tree reduce is coalesced
        ws_e[(size_t)threadIdx.x * EGRID + blockIdx.x] = s;
    }
}

// one block per (g, slot) pair: coalesced reduce of EGRID partials -> G54
__global__ void __launch_bounds__(256)
k_ereduce(const float* __restrict__ ws_e, float* __restrict__ G54,
          int g0, int g1, int g2)
{
    const int p = blockIdx.x;            // 0..53
    const int g = p / 18, slot = p % 18;
    int grids[3] = {g0, g1, g2};
    const int gb = grids[g];
    const float* base = ws_e + (size_t)g * 18 * EGRID + (size_t)slot * EGRID;

    const int t = threadIdx.x;
    float s = 0.f;
    for (int bb = t; bb < gb; bb += 256) s += base[bb];
    #pragma unroll
    for (int o = 32; o; o >>= 1) s += __shfl_xor(s, o);

    __shared__ float wr[4];
    if ((t & 63) == 0) wr[t >> 6] = s;
    __syncthreads();
    if (t == 0) G54[p] = wr[0] + wr[1] + wr[2] + wr[3];
}

__global__ void __launch_bounds__(256)
k_final(const float* __restrict__ ws_red, const float* __restrict__ G54,
        const void* __restrict__ lamda_ptr, float* __restrict__ out, int n)
{
    __shared__ float G[54];
    const int t = threadIdx.x;
    if (t < 54) G[t] = G54[t];
    __syncthreads();

    const float* P  = ws_red;
    const float* cs = ws_red + 4096;

    const float scale = 1.0507009873554805f;
    const float alpha = 1.6732632423543772f;
    for (int idx = t; idx < 4096; idx += 256) {
        int k = idx >> 8;
        float x = P[idx] / cs[k];
        float y = x > 0.f ? scale * x : scale * alpha * (expf(x) - 1.f);
        out[idx] = y;
    }

    if (t == 0) {
        int   li = *(const int*)lamda_ptr;
        float lf = *(const float*)lamda_ptr;
        float lamda = (li > -100000 && li < 100000) ? (float)li : lf;

        float m = G[0], trA = G[1];
        float ds2 = 0.f;
        for (int k = 0; k < 16; ++k) ds2 += G[2 + k] * G[2 + k];
        float spectral = -(trA - ds2 / (2.f * m)) / (2.f * m);

        float Q[2], gm[2];
        for (int g = 0; g < 2; ++g) {
            const float* Gg = G + 18 * (g + 1);
            float mg = Gg[0], trg = Gg[1];
            float gds2 = 0.f;
            for (int k = 0; k < 16; ++k) gds2 += Gg[2 + k] * Gg[2 + k];
            float safe = mg > 0.f ? mg : 1.f;
            float q = (trg - gds2 / (2.f * safe)) / (2.f * m);
            Q[g]  = mg > 0.f ? q : 0.f;
            gm[g] = mg;
        }
        float Qmin = fminf(Q[0], Q[1]);
        float gmean = 0.5f * (gm[0] + gm[1]);
        float fairness = (m / (gmean + 1e-8f)) * (-Qmin);

        float csn = 0.f;
        for (int k = 0; k < 16; ++k) csn += cs[k] * cs[k];
        float collapse = (sqrtf(csn) / (float)n) * 4.f - 1.f;   // sqrt(16)=4

        out[4096 + (size_t)n * 16] = spectral + lamda * fairness + 0.1f * collapse;
    }
}

extern "C" void kernel_launch(void* const* d_in, const int* in_sizes, int n_in,
                              void* d_out, int out_size, void* d_ws, size_t ws_size,
                              hipStream_t stream)
{
    const float* F       = (const float*)d_in[0];
    const float* W       = (const float*)d_in[1];
    const float* b       = (const float*)d_in[2];
    const int*   adj_src = (const int*)d_in[3];
    const int*   adj_dst = (const int*)d_in[4];
    const float* adj_val = (const float*)d_in[5];
    const int*   g1_src  = (const int*)d_in[6];
    const int*   g1_dst  = (const int*)d_in[7];
    const float* g1_val  = (const float*)d_in[8];
    const int*   g2_src  = (const int*)d_in[9];
    const int*   g2_dst  = (const int*)d_in[10];
    const float* g2_val  = (const float*)d_in[11];
    const void*  lamda_p = d_in[12];

    const int n  = in_sizes[0] / 256;
    const int nE = in_sizes[3];
    const int n1 = in_sizes[6];
    const int n2 = in_sizes[9];

    float* out   = (float*)d_out;
    float* S_out = out + 4096;          // S lives directly in d_out
    float* ws    = (float*)d_ws;
    float* ws_e  = ws + OFF_E;
    float* ws_r  = ws + OFF_R;
    float* ws_g  = ws + OFF_G;

    const int n_tiles = (n + 15) >> 4;
    int grid1 = n_tiles < G1_MAX ? n_tiles : G1_MAX;

    k_rows<<<grid1, 256, 0, stream>>>(F, W, b, S_out, ws, n, n_tiles);

    hipMemsetAsync(ws_r, 0, 4112 * sizeof(float), stream);
    k_reduce<<<17 * NSEG, 256, 0, stream>>>(ws, ws_r, grid1);

    auto eg = [](int ne) { int g = (ne + 255) / 256; return g < EGRID ? g : EGRID; };
    k_edges<<<eg(nE), 256, 0, stream>>>(adj_src, adj_dst, adj_val, S_out,
                                        ws_e + (size_t)0 * 18 * EGRID, nE);
    k_edges<<<eg(n1), 256, 0, stream>>>(g1_src, g1_dst, g1_val, S_out,
                                        ws_e + (size_t)1 * 18 * EGRID, n1);
    k_edges<<<eg(n2), 256, 0, stream>>>(g2_src, g2_dst, g2_val, S_out,
                                        ws_e + (size_t)2 * 18 * EGRID, n2);

    k_ereduce<<<54, 256, 0, stream>>>(ws_e, ws_g, eg(nE), eg(n1), eg(n2));
    k_final<<<1, 256, 0, stream>>>(ws_r, ws_g, lamda_p, out, n);
}

// Round 4
// 172.968 us; speedup vs baseline: 3.6159x; 1.2522x over previous
//
#include <hip/hip_runtime.h>
#include <hip/hip_fp16.h>
#include <cstddef>

// ---------------------------------------------------------------------------
// MultiGroupDMoN forward, reduced algebraically:
//   trace(S^T A S)  = sum_e val * dot(S[src], S[dst])
//   deg @ S         = sum_e val * S[dst, :]
//   m               = sum_e val
// R4: fp16 shadow S (3.2MB, fits per-XCD L2) for edge gathers; 4-edge
//     vectorized, fused single edge kernel for all 3 graphs.
// ws layout (floats):
//   [0 .. G1*4112)                 per-block k_rows partials (4096 P + 16 cs)
//   [OFF_E .. OFF_E+3*18*EGRID)    edge partials, [g][slot][block]
//   [OFF_R .. OFF_R+4112)          reduced P[4096] + cs[16]
//   [OFF_G .. OFF_G+54)            reduced edge accumulators 3 x {m,tr,gdS16}
//   [OFF_H .. OFF_H+n*16 halfs)    fp16 copy of S
// ---------------------------------------------------------------------------

#define G1_MAX   1024
#define EGRID    2048
#define OFF_E    ((size_t)G1_MAX * 4112)
#define OFF_R    (OFF_E + (size_t)3 * 18 * EGRID)
#define OFF_G    (OFF_R + 4112)
#define OFF_H    (OFF_G + 64)

__global__ void __launch_bounds__(256)
k_rows(const float* __restrict__ F, const float* __restrict__ W,
       const float* __restrict__ b, float* __restrict__ S_out,
       __half* __restrict__ S_h, float* __restrict__ ws_P, int n, int n_tiles)
{
    __shared__ float Wt[16][260];     // W transposed, padded
    __shared__ float rows[16][260];   // 16 feature rows, padded
    __shared__ float S_lds[16][17];
    __shared__ float cs_red[256];

    const int t = threadIdx.x;

    for (int idx = t; idx < 4096; idx += 256)
        Wt[idx & 15][idx >> 4] = W[idx];          // Wt[k][d] = W[d][k]

    const float bk = b[t & 15];
    const int rl = t >> 4;       // logits phase: row within tile
    const int kl = t & 15;       // logits phase: cluster
    const int kp = t & 15;       // P phase: cluster
    const int cp = t >> 4;       // P phase: 16-wide d-chunk

    float4 P0 = {0,0,0,0}, P1 = {0,0,0,0}, P2 = {0,0,0,0}, P3 = {0,0,0,0};
    float cs_acc = 0.f;
    __syncthreads();

    for (int tile = blockIdx.x; tile < n_tiles; tile += gridDim.x) {
        const int row0 = tile << 4;
        const float4* F4 = (const float4*)(F + (size_t)row0 * 256);
        #pragma unroll
        for (int q = 0; q < 4; ++q) {
            int idx = t + (q << 8);              // 0..1023 float4 slots
            int r = idx >> 6, dc = idx & 63;
            float4 v = {0.f, 0.f, 0.f, 0.f};
            if (row0 + r < n) v = F4[idx];
            *(float4*)&rows[r][dc << 2] = v;
        }
        __syncthreads();

        // ---- logits: thread (rl, kl) computes F[row0+rl] . W[:,kl] ----
        float acc = 0.f;
        #pragma unroll 8
        for (int dd = 0; dd < 64; ++dd) {
            float4 f4 = *(const float4*)&rows[rl][dd << 2];
            float4 w4 = *(const float4*)&Wt[kl][dd << 2];
            acc = fmaf(f4.x, w4.x, acc);
            acc = fmaf(f4.y, w4.y, acc);
            acc = fmaf(f4.z, w4.z, acc);
            acc = fmaf(f4.w, w4.w, acc);
        }
        acc += bk;

        // ---- softmax over the 16 lanes of this row ----
        float mx = acc;
        #pragma unroll
        for (int o = 8; o; o >>= 1) mx = fmaxf(mx, __shfl_xor(mx, o, 16));
        float ev = __expf(acc - mx);
        float sm = ev;
        #pragma unroll
        for (int o = 8; o; o >>= 1) sm += __shfl_xor(sm, o, 16);
        float sval = ev / sm;

        const bool valid = (row0 + rl) < n;
        if (valid) {
            S_out[(((size_t)(row0 + rl)) << 4) + kl] = sval;  // coalesced
            S_h[(((size_t)(row0 + rl)) << 4) + kl] = __float2half(sval);
            cs_acc += sval;
        }
        S_lds[rl][kl] = valid ? sval : 0.f;
        __syncthreads();

        // ---- P accumulation: thread (kp,cp) owns P[kp][16cp..16cp+15] ----
        #pragma unroll 4
        for (int r = 0; r < 16; ++r) {
            float sv = S_lds[r][kp];
            const float* rp = &rows[r][cp << 4];
            float4 f0 = *(const float4*)&rp[0];
            float4 f1 = *(const float4*)&rp[4];
            float4 f2 = *(const float4*)&rp[8];
            float4 f3 = *(const float4*)&rp[12];
            P0.x = fmaf(sv, f0.x, P0.x); P0.y = fmaf(sv, f0.y, P0.y);
            P0.z = fmaf(sv, f0.z, P0.z); P0.w = fmaf(sv, f0.w, P0.w);
            P1.x = fmaf(sv, f1.x, P1.x); P1.y = fmaf(sv, f1.y, P1.y);
            P1.z = fmaf(sv, f1.z, P1.z); P1.w = fmaf(sv, f1.w, P1.w);
            P2.x = fmaf(sv, f2.x, P2.x); P2.y = fmaf(sv, f2.y, P2.y);
            P2.z = fmaf(sv, f2.z, P2.z); P2.w = fmaf(sv, f2.w, P2.w);
            P3.x = fmaf(sv, f3.x, P3.x); P3.y = fmaf(sv, f3.y, P3.y);
            P3.z = fmaf(sv, f3.z, P3.z); P3.w = fmaf(sv, f3.w, P3.w);
        }
        __syncthreads();   // before next tile overwrites rows[]
    }

    // ---- flush partials to private per-block slot (NO atomics) ----
    {
        float* dst = ws_P + (size_t)blockIdx.x * 4112 + kp * 256 + (cp << 4);
        *(float4*)&dst[0]  = P0;
        *(float4*)&dst[4]  = P1;
        *(float4*)&dst[8]  = P2;
        *(float4*)&dst[12] = P3;
    }
    cs_red[t] = cs_acc;
    __syncthreads();
    if (t < 16) {
        float ssum = 0.f;
        #pragma unroll
        for (int i = 0; i < 16; ++i) ssum += cs_red[t + (i << 4)];
        ws_P[(size_t)blockIdx.x * 4112 + 4096 + t] = ssum;
    }
}

// sums nb per-block partials (stride 4112) into ws_red[0..4111]
#define NSEG 16
__global__ void __launch_bounds__(256)
k_reduce(const float* __restrict__ ws_P, float* __restrict__ ws_red, int nb)
{
    const int seg  = blockIdx.x & (NSEG - 1);
    const int jblk = blockIdx.x / NSEG;
    const int idx  = jblk * 256 + threadIdx.x;
    if (idx >= 4112) return;
    const int chunk = (nb + NSEG - 1) / NSEG;
    const int b0 = seg * chunk;
    const int b1 = min(nb, b0 + chunk);
    float s = 0.f;
    for (int bb = b0; bb < b1; ++bb)
        s += ws_P[(size_t)bb * 4112 + idx];
    atomicAdd(&ws_red[idx], s);
}

// fused edge kernel: blocks [0,g0) -> adj, [g0,g0+g1) -> graph1, rest -> graph2
__global__ void __launch_bounds__(256)
k_edges_all(const int* __restrict__ src0, const int* __restrict__ dst0,
            const float* __restrict__ val0, int n0,
            const int* __restrict__ src1, const int* __restrict__ dst1,
            const float* __restrict__ val1, int n1,
            const int* __restrict__ src2, const int* __restrict__ dst2,
            const float* __restrict__ val2, int n2,
            const __half* __restrict__ S_h, float* __restrict__ ws_e,
            int b0, int b1)
{
    int g, bb, nblk;
    const int* src; const int* dst; const float* val; int nE;
    if ((int)blockIdx.x < b0)      { g = 0; bb = blockIdx.x;          nblk = b0; src = src0; dst = dst0; val = val0; nE = n0; }
    else if ((int)blockIdx.x < b1) { g = 1; bb = blockIdx.x - b0;     nblk = b1 - b0; src = src1; dst = dst1; val = val1; nE = n1; }
    else                           { g = 2; bb = blockIdx.x - b1;     nblk = gridDim.x - b1; src = src2; dst = dst2; val = val2; nE = n2; }

    float m_acc = 0.f, tr_acc = 0.f;
    float gds[16];
    #pragma unroll
    for (int k = 0; k < 16; ++k) gds[k] = 0.f;

    const int nv = nE >> 2;                 // 4 edges per thread-iter
    const int stride = nblk * 256;
    for (int i = bb * 256 + threadIdx.x; i < nv; i += stride) {
        int4   s4 = ((const int4*)src)[i];
        int4   d4 = ((const int4*)dst)[i];
        float4 v4 = ((const float4*)val)[i];
        #pragma unroll
        for (int e = 0; e < 4; ++e) {
            int   si = (&s4.x)[e];
            int   di = (&d4.x)[e];
            float v  = (&v4.x)[e];
            uint4 sa = *(const uint4*)(S_h + ((size_t)si << 4));
            uint4 sb = *(const uint4*)(S_h + ((size_t)si << 4) + 8);
            uint4 da = *(const uint4*)(S_h + ((size_t)di << 4));
            uint4 db = *(const uint4*)(S_h + ((size_t)di << 4) + 8);
            float dot = 0.f;
            float dv[16];
            #pragma unroll
            for (int j = 0; j < 4; ++j) {
                float2 as = __half22float2(*(const __half2*)(&(&sa.x)[j]));
                float2 ad = __half22float2(*(const __half2*)(&(&da.x)[j]));
                float2 bs = __half22float2(*(const __half2*)(&(&sb.x)[j]));
                float2 bd = __half22float2(*(const __half2*)(&(&db.x)[j]));
                dot = fmaf(as.x, ad.x, dot); dot = fmaf(as.y, ad.y, dot);
                dot = fmaf(bs.x, bd.x, dot); dot = fmaf(bs.y, bd.y, dot);
                dv[2*j]     = ad.x; dv[2*j + 1] = ad.y;
                dv[8 + 2*j] = bd.x; dv[9 + 2*j] = bd.y;
            }
            m_acc += v;
            tr_acc = fmaf(v, dot, tr_acc);
            #pragma unroll
            for (int k = 0; k < 16; ++k) gds[k] = fmaf(v, dv[k], gds[k]);
        }
    }

    // wave reduction (64 lanes)
    #pragma unroll
    for (int o = 32; o; o >>= 1) {
        m_acc  += __shfl_xor(m_acc, o);
        tr_acc += __shfl_xor(tr_acc, o);
        #pragma unroll
        for (int k = 0; k < 16; ++k) gds[k] += __shfl_xor(gds[k], o);
    }
    __shared__ float wred[4][18];
    const int wid = threadIdx.x >> 6, lane = threadIdx.x & 63;
    if (lane == 0) {
        wred[wid][0] = m_acc; wred[wid][1] = tr_acc;
        #pragma unroll
        for (int k = 0; k < 16; ++k) wred[wid][2 + k] = gds[k];
    }
    __syncthreads();
    if (threadIdx.x < 18) {
        float s = wred[0][threadIdx.x] + wred[1][threadIdx.x]
                + wred[2][threadIdx.x] + wred[3][threadIdx.x];
        ws_e[(size_t)g * 18 * EGRID + (size_t)threadIdx.x * EGRID + bb] = s;
    }
}

// one block per (g, slot) pair: coalesced reduce of per-graph partials -> G54
__global__ void __launch_bounds__(256)
k_ereduce(const float* __restrict__ ws_e, float* __restrict__ G54,
          int g0, int g1, int g2)
{
    const int p = blockIdx.x;            // 0..53
    const int g = p / 18, slot = p % 18;
    int grids[3] = {g0, g1, g2};
    const int gb = grids[g];
    const float* base = ws_e + (size_t)g * 18 * EGRID + (size_t)slot * EGRID;

    const int t = threadIdx.x;
    float s = 0.f;
    for (int bb = t; bb < gb; bb += 256) s += base[bb];
    #pragma unroll
    for (int o = 32; o; o >>= 1) s += __shfl_xor(s, o);

    __shared__ float wr[4];
    if ((t & 63) == 0) wr[t >> 6] = s;
    __syncthreads();
    if (t == 0) G54[p] = wr[0] + wr[1] + wr[2] + wr[3];
}

__global__ void __launch_bounds__(256)
k_final(const float* __restrict__ ws_red, const float* __restrict__ G54,
        const void* __restrict__ lamda_ptr, float* __restrict__ out, int n)
{
    __shared__ float G[54];
    const int t = threadIdx.x;
    if (t < 54) G[t] = G54[t];
    __syncthreads();

    const float* P  = ws_red;
    const float* cs = ws_red + 4096;

    const float scale = 1.0507009873554805f;
    const float alpha = 1.6732632423543772f;
    for (int idx = t; idx < 4096; idx += 256) {
        int k = idx >> 8;
        float x = P[idx] / cs[k];
        float y = x > 0.f ? scale * x : scale * alpha * (expf(x) - 1.f);
        out[idx] = y;
    }

    if (t == 0) {
        int   li = *(const int*)lamda_ptr;
        float lf = *(const float*)lamda_ptr;
        float lamda = (li > -100000 && li < 100000) ? (float)li : lf;

        float m = G[0], trA = G[1];
        float ds2 = 0.f;
        for (int k = 0; k < 16; ++k) ds2 += G[2 + k] * G[2 + k];
        float spectral = -(trA - ds2 / (2.f * m)) / (2.f * m);

        float Q[2], gm[2];
        for (int g = 0; g < 2; ++g) {
            const float* Gg = G + 18 * (g + 1);
            float mg = Gg[0], trg = Gg[1];
            float gds2 = 0.f;
            for (int k = 0; k < 16; ++k) gds2 += Gg[2 + k] * Gg[2 + k];
            float safe = mg > 0.f ? mg : 1.f;
            float q = (trg - gds2 / (2.f * safe)) / (2.f * m);
            Q[g]  = mg > 0.f ? q : 0.f;
            gm[g] = mg;
        }
        float Qmin = fminf(Q[0], Q[1]);
        float gmean = 0.5f * (gm[0] + gm[1]);
        float fairness = (m / (gmean + 1e-8f)) * (-Qmin);

        float csn = 0.f;
        for (int k = 0; k < 16; ++k) csn += cs[k] * cs[k];
        float collapse = (sqrtf(csn) / (float)n) * 4.f - 1.f;   // sqrt(16)=4

        out[4096 + (size_t)n * 16] = spectral + lamda * fairness + 0.1f * collapse;
    }
}

extern "C" void kernel_launch(void* const* d_in, const int* in_sizes, int n_in,
                              void* d_out, int out_size, void* d_ws, size_t ws_size,
                              hipStream_t stream)
{
    const float* F       = (const float*)d_in[0];
    const float* W       = (const float*)d_in[1];
    const float* b       = (const float*)d_in[2];
    const int*   adj_src = (const int*)d_in[3];
    const int*   adj_dst = (const int*)d_in[4];
    const float* adj_val = (const float*)d_in[5];
    const int*   g1_src  = (const int*)d_in[6];
    const int*   g1_dst  = (const int*)d_in[7];
    const float* g1_val  = (const float*)d_in[8];
    const int*   g2_src  = (const int*)d_in[9];
    const int*   g2_dst  = (const int*)d_in[10];
    const float* g2_val  = (const float*)d_in[11];
    const void*  lamda_p = d_in[12];

    const int n  = in_sizes[0] / 256;
    const int nE = in_sizes[3];
    const int n1 = in_sizes[6];
    const int n2 = in_sizes[9];

    float*  out   = (float*)d_out;
    float*  S_out = out + 4096;          // S lives directly in d_out
    float*  ws    = (float*)d_ws;
    float*  ws_e  = ws + OFF_E;
    float*  ws_r  = ws + OFF_R;
    float*  ws_g  = ws + OFF_G;
    __half* ws_h  = (__half*)(ws + OFF_H);

    const int n_tiles = (n + 15) >> 4;
    int grid1 = n_tiles < G1_MAX ? n_tiles : G1_MAX;

    k_rows<<<grid1, 256, 0, stream>>>(F, W, b, S_out, ws_h, ws, n, n_tiles);

    hipMemsetAsync(ws_r, 0, 4112 * sizeof(float), stream);
    k_reduce<<<17 * NSEG, 256, 0, stream>>>(ws, ws_r, grid1);

    // blocks per graph (4 edges/thread)
    auto eg = [](int ne) { int g = (ne / 4 + 255) / 256; if (g < 1) g = 1; return g < EGRID ? g : EGRID; };
    const int b0 = eg(nE), b1g = eg(n1), b2g = eg(n2);
    k_edges_all<<<b0 + b1g + b2g, 256, 0, stream>>>(
        adj_src, adj_dst, adj_val, nE,
        g1_src, g1_dst, g1_val, n1,
        g2_src, g2_dst, g2_val, n2,
        ws_h, ws_e, b0, b0 + b1g);

    k_ereduce<<<54, 256, 0, stream>>>(ws_e, ws_g, b0, b1g, b2g);
    k_final<<<1, 256, 0, stream>>>(ws_r, ws_g, lamda_p, out, n);
}